// Round 7
// baseline (37.238 us; speedup 1.0000x reference)
//
#include <hip/hip_runtime.h>
#include <math.h>

// B=4, T=S=512, M=N=512, H=128
#define KDIM 512
#define HDIM 128
#define SDIM 512
#define TOTAL_ROWS 2048
#define RPB 4                            // rows per proj block
#define INV_SCALE 0.04419417382415922f   // 1/sqrt(512)

// score[b,t,s] = a'[b,t] + c'[b,s]  (both pre-scaled)
//   a'[b,t] = inv_scale * sum_h v[h]   * tanh(q[b,t,:]·W2[h,:])
//   c'[b,s] = inv_scale * sum_h v[H+h] * tanh(k[b,s,:]·W1[h,:])

__device__ __forceinline__ float fast_tanh(float x) {
    // tanh(x) = 1 - 2/(e^{2x}+1); ~1e-7 abs error, graceful at +/-inf
    float e = __expf(2.0f * x);
    return 1.0f - 2.0f / (e + 1.0f);
}

// 1024 blocks x 256 threads (4 waves). 4 blocks/CU co-resident -> 16 waves/CU = 4/SIMD.
// blocks [0,512): query rows -> ws[0:2048]; [512,1024): keys rows -> ws[2048:4096].
// 4 rows/block. Lane: ks = lane[0:2], kb = lane[3] (K-split 16 in-wave), hgl = lane[4:5];
// hg = wave*4 + hgl (16 h-groups x 8 h = 128).
// Per thread: 1024 FMA, 32 ds_read_b128 (X), 64 global float4 (W, once per block).
// VGPR ~85 (acc 32 + w 32 + misc) <= 128 forced by __launch_bounds__(256,4).
__global__ __launch_bounds__(256, 4) void proj_kernel(
    const float* __restrict__ query, const float* __restrict__ keys,
    const float* __restrict__ W1, const float* __restrict__ W2,
    const float* __restrict__ v, float* __restrict__ ws)
{
    const int blk = blockIdx.x;
    const bool is_keys = (blk >= 512);
    const float* __restrict__ X  = is_keys ? keys : query;
    const float* __restrict__ W  = is_keys ? W1 : W2;
    const float* __restrict__ vv = v + (is_keys ? HDIM : 0);
    float* __restrict__ out = ws + (is_keys ? TOTAL_ROWS : 0);
    const int row0 = (is_keys ? blk - 512 : blk) * RPB;

    __shared__ float sm_x[RPB][KDIM];   // 8 KB
    __shared__ float sm_p[4][RPB];      // [wave][r] partials

    const int tid  = threadIdx.x;     // 0..255
    const int wave = tid >> 6;        // 0..3
    const int lane = tid & 63;
    const int ks   = lane & 7;
    const int kb   = (lane >> 3) & 1;
    const int hgl  = (lane >> 4) & 3;
    const int hg   = wave * 4 + hgl;  // 0..15

    // Stage X tile: 4*512 floats = 512 float4; 2 per thread, coalesced.
    {
        const float4* __restrict__ src = (const float4*)(X + (size_t)row0 * KDIM);
        float4* dst = (float4*)(&sm_x[0][0]);
        dst[tid]       = src[tid];
        dst[tid + 256] = src[tid + 256];
    }
    __syncthreads();

    float acc[RPB][8];
    #pragma unroll
    for (int r = 0; r < RPB; ++r)
        #pragma unroll
        for (int h = 0; h < 8; ++h) acc[r][h] = 0.0f;

    const float* __restrict__ wbase = W + (size_t)(hg * 8) * KDIM;
    const int colbase = kb * 32 + ks * 4;

    // Thread covers K cols {jj*64 + kb*32 + ks*4 .. +3}, jj = 0..7 (32 of 512).
    // Per jj: 8 W float4 (coalesced, once per block across lanes) + 4 X ds_read_b128 + 128 FMA.
    #pragma unroll 2
    for (int jj = 0; jj < 8; ++jj) {
        const int col = jj * 64 + colbase;
        float4 w[8];
        #pragma unroll
        for (int h = 0; h < 8; ++h)
            w[h] = *(const float4*)(wbase + h * KDIM + col);
        #pragma unroll
        for (int r = 0; r < RPB; ++r) {
            const float4 x = *(const float4*)(&sm_x[r][col]);
            #pragma unroll
            for (int h = 0; h < 8; ++h) {
                acc[r][h] = fmaf(x.x, w[h].x, acc[r][h]);
                acc[r][h] = fmaf(x.y, w[h].y, acc[r][h]);
                acc[r][h] = fmaf(x.z, w[h].z, acc[r][h]);
                acc[r][h] = fmaf(x.w, w[h].w, acc[r][h]);
            }
        }
    }

    // K-split reduce over lane bits 0-3 (ks,kb): 32 accs x 4 levels, in-wave.
    #pragma unroll
    for (int r = 0; r < RPB; ++r)
        #pragma unroll
        for (int h = 0; h < 8; ++h) {
            float s = acc[r][h];
            s += __shfl_xor(s, 1, 64);
            s += __shfl_xor(s, 2, 64);
            s += __shfl_xor(s, 4, 64);
            s += __shfl_xor(s, 8, 64);
            acc[r][h] = s;
        }

    const float4 v0 = *(const float4*)(vv + hg * 8);
    const float4 v1 = *(const float4*)(vv + hg * 8 + 4);

    #pragma unroll
    for (int r = 0; r < RPB; ++r) {
        float rs = v0.x * fast_tanh(acc[r][0]) + v0.y * fast_tanh(acc[r][1])
                 + v0.z * fast_tanh(acc[r][2]) + v0.w * fast_tanh(acc[r][3])
                 + v1.x * fast_tanh(acc[r][4]) + v1.y * fast_tanh(acc[r][5])
                 + v1.z * fast_tanh(acc[r][6]) + v1.w * fast_tanh(acc[r][7]);
        // reduce over this wave's 4 h-groups (lane bits 4-5)
        rs += __shfl_xor(rs, 16, 64);
        rs += __shfl_xor(rs, 32, 64);
        if (lane == 0) sm_p[wave][r] = rs;
    }
    __syncthreads();

    if (tid < RPB)
        out[row0 + tid] = (sm_p[0][tid] + sm_p[1][tid] + sm_p[2][tid] + sm_p[3][tid]) * INV_SCALE;
}

// 128 blocks x 256 threads; block covers 16 bt-rows (one batch each: 32 blocks/batch).
// c'[b,:] staged in LDS once per block; each thread writes 8 float4.
__global__ __launch_bounds__(256) void outer_kernel(
    const float* __restrict__ ws, float* __restrict__ out)
{
    __shared__ float sm_c[SDIM];
    __shared__ float sm_a[16];

    const int blk  = blockIdx.x;       // 0..127
    const int row0 = blk * 16;         // bt rows
    const int b    = row0 >> 9;
    const int tid  = threadIdx.x;

    if (tid < 128)
        ((float4*)sm_c)[tid] = ((const float4*)(ws + TOTAL_ROWS + (size_t)b * SDIM))[tid];
    else if (tid < 144)
        sm_a[tid - 128] = ws[row0 + tid - 128];
    __syncthreads();

    const int row = tid >> 4;          // 0..15
    const int cs  = tid & 15;          // col-chunk
    const float a = sm_a[row];
    float4* __restrict__ op = (float4*)(out + (size_t)(row0 + row) * SDIM);
    #pragma unroll
    for (int k = 0; k < 8; ++k) {
        const float4 c = ((const float4*)sm_c)[cs + k * 16];
        float4 o;
        o.x = a + c.x;
        o.y = a + c.y;
        o.z = a + c.z;
        o.w = a + c.w;
        op[cs + k * 16] = o;
    }
}

extern "C" void kernel_launch(void* const* d_in, const int* in_sizes, int n_in,
                              void* d_out, int out_size, void* d_ws, size_t ws_size,
                              hipStream_t stream) {
    const float* query = (const float*)d_in[0];  // (4,512,512)
    const float* keys  = (const float*)d_in[1];  // (4,512,512)
    const float* W1    = (const float*)d_in[2];  // (128,512)
    const float* W2    = (const float*)d_in[3];  // (128,512)
    const float* v     = (const float*)d_in[4];  // (1,256)
    float* out = (float*)d_out;                  // (4,512,512) f32
    float* ws  = (float*)d_ws;                   // a' (2048) + c' (2048) floats

    proj_kernel<<<1024, 256, 0, stream>>>(query, keys, W1, W2, v, ws);
    outer_kernel<<<128, 256, 0, stream>>>(ws, out);
}